// Round 1
// baseline (281.588 us; speedup 1.0000x reference)
//
#include <hip/hip_runtime.h>

// B=4, N=1024, C=256, H=8.
// Reference math collapses: softmax over m sums to 1, and the final einsum
// 'bnmh,bnih->bnih' contracts only m of alpha -> out = vh elementwise.
// So: out[b,n,:] = linear_output^T @ flatten_ih(V-proj(v[b,n,:]) + bias_V)
// Precompose W[j'][j] = sum_{k=i*H+h} V[i,j',h] * L[k,j]  (256x256),
// bvec[j] = sum_k bias_V_flat[k] * L[k,j], then out = v @ W + bvec.
//
// R4 measured 225.4 us; top-5 dispatches all harness d_ws-poison fills
// (512 MB @ ~78 us) -> we control only ~15-25 us.
// R5 change: both kernels' LDS operands are WAVE-UNIFORM (all j-lanes read
// the same v/V value). Route them through the scalar unit instead of LDS:
// uniform-address loads from const __restrict__ become s_load_dwordx4/x8
// (K$), consumed as the 1-SGPR source of v_fmac_f32. Drops all LDS traffic
// + __syncthreads from both kernels.
//   apply_w:  512x ds_read_b128 (6144 cyc/wave) -> 0; VALU floor 3.4 us.
//   compose_w: staging loop + barrier + 4x b128/kk -> 0; VALU floor 1.8 us.

#define ROWS 8     // rows per block in apply kernel

// Kernel 1: split-K GEMM composing W and bvec into workspace (atomicAdd).
// grid = (16 k-chunks of 128, 16 j'-tiles of 16), block = 256 (j).
__global__ __launch_bounds__(256) void compose_w(
    const float* __restrict__ V,    // [C, C, H] : V[i*2048 + j'*8 + h]
    const float* __restrict__ bV,   // [C, H] flat = [2048]
    const float* __restrict__ L,    // [2048, 256]
    float* __restrict__ W2,         // [256*256] (zeroed)
    float* __restrict__ bvec)       // [256] (zeroed)
{
    const int j   = threadIdx.x;
    const int k0  = blockIdx.x * 128;   // multiple of 8 -> octet-aligned
    const int jp0 = blockIdx.y * 16;

    float acc[16];
#pragma unroll
    for (int r = 0; r < 16; ++r) acc[r] = 0.f;
    float accb = 0.f;

    const float* Lp = L + k0 * 256 + j;
    // kk unrolled by 8: within an octet, (k>>3) is constant and (k&7)=0..7,
    // so V[(k>>3)*2048 + (jp0+r)*8 + (k&7)] is 8 CONSECUTIVE floats per r
    // -> s_load_dwordx8 (wave-uniform address). Same for bV[k0+kk].
#pragma unroll 8
    for (int kk = 0; kk < 128; ++kk) {
        const int k = k0 + kk;
        const float lv = Lp[kk * 256];          // coalesced vector load, L2-resident
        accb += bV[k] * lv;                     // uniform -> scalar load
        const float* __restrict__ Vp = V + (k >> 3) * 2048 + jp0 * 8 + (k & 7);
#pragma unroll
        for (int r = 0; r < 16; ++r)
            acc[r] += Vp[r * 8] * lv;           // uniform -> scalar load, SGPR fmac src
    }
#pragma unroll
    for (int r = 0; r < 16; ++r)
        atomicAdd(&W2[(jp0 + r) * 256 + j], acc[r]);
    if (blockIdx.y == 0) atomicAdd(&bvec[j], accb);
}

// Kernel 2: out[row][j] = bvec[j] + sum_j' v[row][j'] * W2[j'][j]
// grid = 4096/ROWS blocks, block = 256 (j). No LDS: v operand is
// wave-uniform -> scalar loads (4 consecutive dwords per (r, jp-chunk)).
__global__ __launch_bounds__(256) void apply_w(
    const float* __restrict__ v,    // [4096, 256]
    const float* __restrict__ W2,   // [256, 256]
    const float* __restrict__ bvec, // [256]
    float* __restrict__ out)        // [4096, 256]
{
    const int j = threadIdx.x;
    const int row0 = blockIdx.x * ROWS;

    const float b = bvec[j];
    float acc[ROWS];
#pragma unroll
    for (int r = 0; r < ROWS; ++r) acc[r] = b;

    const float* Wp = W2 + j;
    const float* __restrict__ vp = v + row0 * 256;

    for (int jp = 0; jp < 256; jp += 4) {
        // 4 coalesced, L2-resident W reads (thread-distinct, overlapped)
        const float w0 = Wp[(jp + 0) * 256];
        const float w1 = Wp[(jp + 1) * 256];
        const float w2 = Wp[(jp + 2) * 256];
        const float w3 = Wp[(jp + 3) * 256];
#pragma unroll
        for (int r = 0; r < ROWS; ++r) {
            // 4 consecutive uniform dwords -> s_load_dwordx4, SGPR fmac srcs
            const float* __restrict__ vr = vp + r * 256 + jp;
            acc[r] += vr[0] * w0 + vr[1] * w1 + vr[2] * w2 + vr[3] * w3;
        }
    }
#pragma unroll
    for (int r = 0; r < ROWS; ++r)
        out[(row0 + r) * 256 + j] = acc[r];
}

extern "C" void kernel_launch(void* const* d_in, const int* in_sizes, int n_in,
                              void* d_out, int out_size, void* d_ws, size_t ws_size,
                              hipStream_t stream) {
    // setup_inputs order: q(0) k(1) v(2) bias(3) atten_mask(4) Q(5) K(6) V(7)
    //                     bias_Q(8) bias_K(9) bias_V(10) linear_output(11)
    const float* v_in = (const float*)d_in[2];
    const float* V_w  = (const float*)d_in[7];
    const float* bV   = (const float*)d_in[10];
    const float* L    = (const float*)d_in[11];

    float* W2   = (float*)d_ws;           // 256*256 floats
    float* bvec = W2 + 256 * 256;         // 256 floats

    hipMemsetAsync(d_ws, 0, (256 * 256 + 256) * sizeof(float), stream);
    compose_w<<<dim3(16, 16), 256, 0, stream>>>(V_w, bV, L, W2, bvec);
    apply_w<<<4096 / ROWS, 256, 0, stream>>>(v_in, W2, bvec, (float*)d_out);
}

// Round 2
// 247.186 us; speedup vs baseline: 1.1392x; 1.1392x over previous
//
#include <hip/hip_runtime.h>

// B=4, N=1024, C=256, H=8.
// Reference math collapses: softmax over m sums to 1, and the final einsum
// 'bnmh,bnih->bnih' contracts only m of alpha -> out = vh elementwise.
// So: out[b,n,:] = linear_output^T @ flatten_ih(V-proj(v[b,n,:]) + bias_V)
// Precompose W[j'][j] = sum_{k=i*H+h} V[i,j',h] * L[k,j]  (256x256),
// bvec[j] = sum_k bias_V_flat[k] * L[k,j], then out = v @ W + bvec.
//
// R4 = 225.4 us (LDS version). R5 (uniform->scalar loads) = 281.6 us FAIL:
// hipcc does NOT scalarize uniform global loads in hot loops; they became
// per-lane same-address VMEM loads. Lesson: LDS broadcast is the right
// transport for wave-uniform operands.
// R6: register-tile over j (thread owns a j-quad via float4 global loads of
// W2/L) so the LDS-broadcast operand amortizes over 4 columns:
//   apply_w:  per jp-quad 2 v-b128 + 4 W-b128 -> 32 MACs (1B LDS/MAC, 4x cut)
//             16-row blocks halve W2 L2 traffic (128MB -> 64MB).
//   compose_w: per kk 1 uniform LDS b128 + 1 coalesced L b128 -> 16 MACs.

// Kernel 1: split-K GEMM composing W and bvec into workspace (atomicAdd).
// grid = (16 k-chunks of 128, 16 jp-tiles of 16), block = 256.
// Thread t: wave w = t>>6 owns jp-subquad jp0+4w..+3; lane jq = t&63 owns
// j = 4*jq..+3. acc[4][4], 16 MACs per kk.
__global__ __launch_bounds__(256) void compose_w(
    const float* __restrict__ V,    // [C, C, H] : V[i*2048 + j'*8 + h]
    const float* __restrict__ bV,   // [C, H] flat = [2048]
    const float* __restrict__ L,    // [2048, 256]
    float* __restrict__ W2,         // [256*256] (zeroed)
    float* __restrict__ bvec)       // [256] (zeroed)
{
    const int t   = threadIdx.x;
    const int k0  = blockIdx.x * 128;   // multiple of 8 -> octet-aligned
    const int jp0 = blockIdx.y * 16;
    const int w   = t >> 6;             // wave id 0..3 (uniform within wave)
    const int jq  = t & 63;             // j-quad

    __shared__ float sV[128 * 16];      // sV[kk*16 + r] = V-col (jp0+r) at k0+kk
    __shared__ float sb[128];

    for (int e = t; e < 128 * 16; e += 256) {
        const int kk = e >> 4, r = e & 15;
        const int k = k0 + kk;
        sV[e] = V[(k >> 3) * 2048 + (jp0 + r) * 8 + (k & 7)];
    }
    if (t < 128) sb[t] = bV[k0 + t];
    __syncthreads();

    float acc[4][4];
#pragma unroll
    for (int r = 0; r < 4; ++r)
#pragma unroll
        for (int c = 0; c < 4; ++c) acc[r][c] = 0.f;

    const float* Lbase = L + k0 * 256 + 4 * jq;  // coalesced b128 across wave
#pragma unroll 4
    for (int kk = 0; kk < 128; ++kk) {
        const float4 lq = *reinterpret_cast<const float4*>(Lbase + kk * 256);
        const float4 vf = *reinterpret_cast<const float4*>(&sV[kk * 16 + 4 * w]); // uniform b128 broadcast
        const float vr[4] = {vf.x, vf.y, vf.z, vf.w};
        const float lc[4] = {lq.x, lq.y, lq.z, lq.w};
#pragma unroll
        for (int r = 0; r < 4; ++r)
#pragma unroll
            for (int c = 0; c < 4; ++c) acc[r][c] += vr[r] * lc[c];
    }

#pragma unroll
    for (int r = 0; r < 4; ++r)
#pragma unroll
        for (int c = 0; c < 4; ++c)
            atomicAdd(&W2[(jp0 + 4 * w + r) * 256 + 4 * jq + c], acc[r][c]);

    // bias: wave 0 of the jp0==0 blocks re-walks its k-chunk (L is L2-warm).
    if (blockIdx.y == 0 && w == 0) {
        float ab[4] = {0.f, 0.f, 0.f, 0.f};
        for (int kk = 0; kk < 128; ++kk) {
            const float4 lq = *reinterpret_cast<const float4*>(Lbase + kk * 256);
            const float s = sb[kk];
            ab[0] += s * lq.x; ab[1] += s * lq.y;
            ab[2] += s * lq.z; ab[3] += s * lq.w;
        }
#pragma unroll
        for (int c = 0; c < 4; ++c) atomicAdd(&bvec[4 * jq + c], ab[c]);
    }
}

// Kernel 2: out[row][j] = bvec[j] + sum_j' v[row][j'] * W2[j'][j]
// grid = (4096/16 rows, 2 j-halves), block = 256 (8 waves... 4 waves, 2 blk/CU).
// Thread t: rg = t>>5 -> rows row0+2*rg+{0,1}; jq = t&31 -> j = j0+4*jq+{0..3}.
// Per jp-quad: 2 LDS b128 (2-way broadcast, conflict-free) + 4 global W b128
// (coalesced, L2-resident) -> 32 fmacs.
__global__ __launch_bounds__(256) void apply_w(
    const float* __restrict__ v,    // [4096, 256]
    const float* __restrict__ W2,   // [256, 256]
    const float* __restrict__ bvec, // [256]
    float* __restrict__ out)        // [4096, 256]
{
    const int t    = threadIdx.x;
    const int row0 = blockIdx.x * 16;
    const int j0   = blockIdx.y * 128;
    const int rg   = t >> 5;                 // 0..7
    const int jq   = t & 31;                 // 0..31
    const int jcol = j0 + 4 * jq;
    const int r0   = row0 + 2 * rg;

    __shared__ float sv[16 * 256];
    {
        const float4* v4 = reinterpret_cast<const float4*>(v + row0 * 256);
        float4* sv4 = reinterpret_cast<float4*>(sv);
#pragma unroll
        for (int e = t; e < 16 * 64; e += 256) sv4[e] = v4[e];
    }
    __syncthreads();

    const float4 bq = *reinterpret_cast<const float4*>(bvec + jcol);
    float4 acc0 = bq, acc1 = bq;

    const float* svr0 = sv + (2 * rg + 0) * 256;
    const float* svr1 = sv + (2 * rg + 1) * 256;
    const float* Wp = W2 + jcol;

#pragma unroll 2
    for (int jp = 0; jp < 256; jp += 4) {
        const float4 w0 = *reinterpret_cast<const float4*>(Wp + (jp + 0) * 256);
        const float4 w1 = *reinterpret_cast<const float4*>(Wp + (jp + 1) * 256);
        const float4 w2 = *reinterpret_cast<const float4*>(Wp + (jp + 2) * 256);
        const float4 w3 = *reinterpret_cast<const float4*>(Wp + (jp + 3) * 256);
        const float4 a = *reinterpret_cast<const float4*>(svr0 + jp);
        const float4 b = *reinterpret_cast<const float4*>(svr1 + jp);

        acc0.x += a.x * w0.x + a.y * w1.x + a.z * w2.x + a.w * w3.x;
        acc0.y += a.x * w0.y + a.y * w1.y + a.z * w2.y + a.w * w3.y;
        acc0.z += a.x * w0.z + a.y * w1.z + a.z * w2.z + a.w * w3.z;
        acc0.w += a.x * w0.w + a.y * w1.w + a.z * w2.w + a.w * w3.w;

        acc1.x += b.x * w0.x + b.y * w1.x + b.z * w2.x + b.w * w3.x;
        acc1.y += b.x * w0.y + b.y * w1.y + b.z * w2.y + b.w * w3.y;
        acc1.z += b.x * w0.z + b.y * w1.z + b.z * w2.z + b.w * w3.z;
        acc1.w += b.x * w0.w + b.y * w1.w + b.z * w2.w + b.w * w3.w;
    }

    *reinterpret_cast<float4*>(out + (r0 + 0) * 256 + jcol) = acc0;
    *reinterpret_cast<float4*>(out + (r0 + 1) * 256 + jcol) = acc1;
}

extern "C" void kernel_launch(void* const* d_in, const int* in_sizes, int n_in,
                              void* d_out, int out_size, void* d_ws, size_t ws_size,
                              hipStream_t stream) {
    // setup_inputs order: q(0) k(1) v(2) bias(3) atten_mask(4) Q(5) K(6) V(7)
    //                     bias_Q(8) bias_K(9) bias_V(10) linear_output(11)
    const float* v_in = (const float*)d_in[2];
    const float* V_w  = (const float*)d_in[7];
    const float* bV   = (const float*)d_in[10];
    const float* L    = (const float*)d_in[11];

    float* W2   = (float*)d_ws;           // 256*256 floats
    float* bvec = W2 + 256 * 256;         // 256 floats

    hipMemsetAsync(d_ws, 0, (256 * 256 + 256) * sizeof(float), stream);
    compose_w<<<dim3(16, 16), 256, 0, stream>>>(V_w, bV, L, W2, bvec);
    apply_w<<<dim3(4096 / 16, 2), 256, 0, stream>>>(v_in, W2, bvec, (float*)d_out);
}

// Round 4
// 243.283 us; speedup vs baseline: 1.1575x; 1.0160x over previous
//
#include <hip/hip_runtime.h>

// B=4, N=1024, C=256, H=8.
// Reference math collapses: softmax over m sums to 1, and the final einsum
// 'bnmh,bnih->bnih' contracts only m of alpha -> out = vh elementwise.
// So: out[b,n,:] = linear_output^T @ flatten_ih(V-proj(v[b,n,:]) + bias_V)
// Precompose W[j'][j] = sum_{k=i*H+h} V[i,j',h] * L[k,j]  (256x256),
// bvec[j] = sum_k bias_V_flat[k] * L[k,j], then out = v @ W + bvec.
//
// History: R4 (v-in-LDS apply) 225.4. R5 (scalarize uniform) 281.6 FAIL
// (hipcc emits per-lane VMEM for uniform loads). R6 (reg-tile, W global)
// 247.2 on a distressed node. R7 (W-in-LDS, 128 KB static shared) --
// container failed twice; 128 KB static __shared__ exceeds the default
// 64 KB per-WG static LDS cap and is the prime in-kernel suspect.
// R8 = R7 theory with a guaranteed-legal 64 KB tile:
//   apply_w: sW[256][64] in LDS, read at lane-DISTINCT contiguous addrs
//   (conflict-free ds_read_b128; 4-way same-addr broadcast is free);
//   v streamed as lane-uniform 16B global loads (single-line, reused x16).
//   Per jp-quad: 4 LDS b128 + 4 v b128 -> 64 fmacs. Per-CU: LDS ~5.1 us,
//   VALU ~3.4 us overlapped -> ~5-6 us vs R4's ~14 us.
// compose_w: R6 form (1 uniform LDS b128 + 1 coalesced L b128 per kk).

// Kernel 1: split-K GEMM composing W and bvec into workspace (atomicAdd).
// grid = (16 k-chunks of 128, 16 jp-tiles of 16), block = 256.
__global__ __launch_bounds__(256) void compose_w(
    const float* __restrict__ V,    // [C, C, H] : V[i*2048 + j'*8 + h]
    const float* __restrict__ bV,   // [C, H] flat = [2048]
    const float* __restrict__ L,    // [2048, 256]
    float* __restrict__ W2,         // [256*256] (zeroed)
    float* __restrict__ bvec)       // [256] (zeroed)
{
    const int t   = threadIdx.x;
    const int k0  = blockIdx.x * 128;
    const int jp0 = blockIdx.y * 16;
    const int w   = t >> 6;             // wave id 0..3 (uniform within wave)
    const int jq  = t & 63;             // j-quad

    __shared__ float sV[128 * 16];      // sV[kk*16 + r] = V-col (jp0+r) at k0+kk
    __shared__ float sb[128];

    for (int e = t; e < 128 * 16; e += 256) {
        const int kk = e >> 4, r = e & 15;
        const int k = k0 + kk;
        sV[e] = V[(k >> 3) * 2048 + (jp0 + r) * 8 + (k & 7)];
    }
    if (t < 128) sb[t] = bV[k0 + t];
    __syncthreads();

    float acc[4][4];
#pragma unroll
    for (int r = 0; r < 4; ++r)
#pragma unroll
        for (int c = 0; c < 4; ++c) acc[r][c] = 0.f;

    const float* Lbase = L + k0 * 256 + 4 * jq;  // coalesced b128 across wave
#pragma unroll 4
    for (int kk = 0; kk < 128; ++kk) {
        const float4 lq = *reinterpret_cast<const float4*>(Lbase + kk * 256);
        const float4 vf = *reinterpret_cast<const float4*>(&sV[kk * 16 + 4 * w]); // uniform b128 broadcast
        const float vr[4] = {vf.x, vf.y, vf.z, vf.w};
        const float lc[4] = {lq.x, lq.y, lq.z, lq.w};
#pragma unroll
        for (int r = 0; r < 4; ++r)
#pragma unroll
            for (int c = 0; c < 4; ++c) acc[r][c] += vr[r] * lc[c];
    }

#pragma unroll
    for (int r = 0; r < 4; ++r)
#pragma unroll
        for (int c = 0; c < 4; ++c)
            atomicAdd(&W2[(jp0 + 4 * w + r) * 256 + 4 * jq + c], acc[r][c]);

    // bias: wave 0 of the jp0==0 blocks re-walks its k-chunk (L is L2-warm).
    if (blockIdx.y == 0 && w == 0) {
        float ab[4] = {0.f, 0.f, 0.f, 0.f};
        for (int kk = 0; kk < 128; ++kk) {
            const float4 lq = *reinterpret_cast<const float4*>(Lbase + kk * 256);
            const float s = sb[kk];
            ab[0] += s * lq.x; ab[1] += s * lq.y;
            ab[2] += s * lq.z; ab[3] += s * lq.w;
        }
#pragma unroll
        for (int c = 0; c < 4; ++c) atomicAdd(&bvec[4 * jq + c], ab[c]);
    }
}

// Kernel 2: out[row][j] = bvec[j] + sum_j' v[row][j'] * W2[j'][j]
// W tile [256 jp][64 j] staged in LDS (64 KB). grid = (4096/64, 4), block 256.
// Thread t: jq = t&15 -> j = j0+4*jq..+3 (lane-distinct); rg = t>>4 -> rows
// r0 = row0+4*rg..+3. Per jp-quad: 4 ds_read_b128 of W (16 distinct 16B
// segments spanning 256B -> 2-way bank alias (free) + 4-way same-addr
// broadcast (free)) + 4 lane-uniform v b128 loads -> 64 fmacs.
__global__ __launch_bounds__(256) void apply_w(
    const float* __restrict__ v,    // [4096, 256]
    const float* __restrict__ W2,   // [256, 256]
    const float* __restrict__ bvec, // [256]
    float* __restrict__ out)        // [4096, 256]
{
    const int t    = threadIdx.x;
    const int row0 = blockIdx.x * 64;
    const int j0   = blockIdx.y * 64;
    const int jq   = t & 15;                 // j-quad within tile
    const int rg   = t >> 4;                 // 0..15
    const int jcol = j0 + 4 * jq;
    const int r0   = row0 + 4 * rg;

    __shared__ float sW[256 * 64];           // sW[jp][jj], jj = j - j0 : 64 KB
    {
        // 256*16 float4 = 4096; 16 per thread, fully coalesced.
        for (int e = t; e < 256 * 16; e += 256) {
            const int jp = e >> 4, q = e & 15;
            *reinterpret_cast<float4*>(&sW[jp * 64 + 4 * q]) =
                *reinterpret_cast<const float4*>(W2 + jp * 256 + j0 + 4 * q);
        }
    }
    __syncthreads();

    const float4 bq = *reinterpret_cast<const float4*>(bvec + jcol);
    float4 acc0 = bq, acc1 = bq, acc2 = bq, acc3 = bq;

    const float* vb = v + r0 * 256;
    const float* sWp = sW + 4 * jq;

#pragma unroll 2
    for (int jp = 0; jp < 256; jp += 4) {
        const float4 w0 = *reinterpret_cast<const float4*>(sWp + (jp + 0) * 64);
        const float4 w1 = *reinterpret_cast<const float4*>(sWp + (jp + 1) * 64);
        const float4 w2 = *reinterpret_cast<const float4*>(sWp + (jp + 2) * 64);
        const float4 w3 = *reinterpret_cast<const float4*>(sWp + (jp + 3) * 64);

        const float4 a0 = *reinterpret_cast<const float4*>(vb + 0 * 256 + jp);
        const float4 a1 = *reinterpret_cast<const float4*>(vb + 1 * 256 + jp);
        const float4 a2 = *reinterpret_cast<const float4*>(vb + 2 * 256 + jp);
        const float4 a3 = *reinterpret_cast<const float4*>(vb + 3 * 256 + jp);

        acc0.x += a0.x * w0.x + a0.y * w1.x + a0.z * w2.x + a0.w * w3.x;
        acc0.y += a0.x * w0.y + a0.y * w1.y + a0.z * w2.y + a0.w * w3.y;
        acc0.z += a0.x * w0.z + a0.y * w1.z + a0.z * w2.z + a0.w * w3.z;
        acc0.w += a0.x * w0.w + a0.y * w1.w + a0.z * w2.w + a0.w * w3.w;

        acc1.x += a1.x * w0.x + a1.y * w1.x + a1.z * w2.x + a1.w * w3.x;
        acc1.y += a1.x * w0.y + a1.y * w1.y + a1.z * w2.y + a1.w * w3.y;
        acc1.z += a1.x * w0.z + a1.y * w1.z + a1.z * w2.z + a1.w * w3.z;
        acc1.w += a1.x * w0.w + a1.y * w1.w + a1.z * w2.w + a1.w * w3.w;

        acc2.x += a2.x * w0.x + a2.y * w1.x + a2.z * w2.x + a2.w * w3.x;
        acc2.y += a2.x * w0.y + a2.y * w1.y + a2.z * w2.y + a2.w * w3.y;
        acc2.z += a2.x * w0.z + a2.y * w1.z + a2.z * w2.z + a2.w * w3.z;
        acc2.w += a2.x * w0.w + a2.y * w1.w + a2.z * w2.w + a2.w * w3.w;

        acc3.x += a3.x * w0.x + a3.y * w1.x + a3.z * w2.x + a3.w * w3.x;
        acc3.y += a3.x * w0.y + a3.y * w1.y + a3.z * w2.y + a3.w * w3.y;
        acc3.z += a3.x * w0.z + a3.y * w1.z + a3.z * w2.z + a3.w * w3.z;
        acc3.w += a3.x * w0.w + a3.y * w1.w + a3.z * w2.w + a3.w * w3.w;
    }

    *reinterpret_cast<float4*>(out + (r0 + 0) * 256 + jcol) = acc0;
    *reinterpret_cast<float4*>(out + (r0 + 1) * 256 + jcol) = acc1;
    *reinterpret_cast<float4*>(out + (r0 + 2) * 256 + jcol) = acc2;
    *reinterpret_cast<float4*>(out + (r0 + 3) * 256 + jcol) = acc3;
}

extern "C" void kernel_launch(void* const* d_in, const int* in_sizes, int n_in,
                              void* d_out, int out_size, void* d_ws, size_t ws_size,
                              hipStream_t stream) {
    // setup_inputs order: q(0) k(1) v(2) bias(3) atten_mask(4) Q(5) K(6) V(7)
    //                     bias_Q(8) bias_K(9) bias_V(10) linear_output(11)
    const float* v_in = (const float*)d_in[2];
    const float* V_w  = (const float*)d_in[7];
    const float* bV   = (const float*)d_in[10];
    const float* L    = (const float*)d_in[11];

    float* W2   = (float*)d_ws;           // 256*256 floats
    float* bvec = W2 + 256 * 256;         // 256 floats

    hipMemsetAsync(d_ws, 0, (256 * 256 + 256) * sizeof(float), stream);
    compose_w<<<dim3(16, 16), 256, 0, stream>>>(V_w, bV, L, W2, bvec);
    apply_w<<<dim3(4096 / 64, 4), 256, 0, stream>>>(v_in, W2, bvec, (float*)d_out);
}

// Round 5
// 241.370 us; speedup vs baseline: 1.1666x; 1.0079x over previous
//
#include <hip/hip_runtime.h>

// B=4, N=1024, C=256, H=8.
// Reference math collapses: softmax over m sums to 1, and the final einsum
// 'bnmh,bnih->bnih' contracts only m of alpha -> out = vh elementwise.
// So: out[b,n,:] = linear_output^T @ flatten_ih(V-proj(v[b,n,:]) + bias_V)
// Precompose W[j'][j] = sum_{k=i*H+h} V[i,j',h] * L[k,j]  (256x256),
// bvec[j] = sum_k bias_V_flat[k] * L[k,j], then out = v @ W + bvec.
//
// History: R0 (v-in-LDS, 1 j/thr) 225.4. R5 scalarize 281.6 FAIL. R6
// (reg-tile, W global full-stream) 247.2. R8 (W-in-LDS 64KB, 256 blocks)
// 243.3. Diagnosis: R6/R8 regressions = occupancy collapse (R8: 1 blk/CU
// = 1 wave/SIMD -> latency-bound; R0 ran 512 blks, 8KB LDS, ~16+ waves/CU).
// Binding constraint = MACs/LDS-inst x occupancy; blocks = 1M/(256*out_thr)
// forces out/thread <= 8 for >=512 blocks.
// R9 apply: 512 blocks, 33KB LDS (2 blk/CU, 8 waves/CU), thread = 2 rows x
// 4 j over a 32-row x 64-j tile. Per jp-quad: 2 LDS b128 (bank-padded,
// conflict-free) + 4 coalesced W b128 (64-j slice only: 64KB/wave from L2,
// 8x less than R0) -> 32 fmacs = 16 MACs/LDS-inst (4x R0 ratio).
// compose_w: R6 form (1 uniform LDS b128 + 1 coalesced L b128 per kk).

// Kernel 1: split-K GEMM composing W and bvec into workspace (atomicAdd).
// grid = (16 k-chunks of 128, 16 jp-tiles of 16), block = 256.
__global__ __launch_bounds__(256) void compose_w(
    const float* __restrict__ V,    // [C, C, H] : V[i*2048 + j'*8 + h]
    const float* __restrict__ bV,   // [C, H] flat = [2048]
    const float* __restrict__ L,    // [2048, 256]
    float* __restrict__ W2,         // [256*256] (zeroed)
    float* __restrict__ bvec)       // [256] (zeroed)
{
    const int t   = threadIdx.x;
    const int k0  = blockIdx.x * 128;
    const int jp0 = blockIdx.y * 16;
    const int w   = t >> 6;             // wave id 0..3 (uniform within wave)
    const int jq  = t & 63;             // j-quad

    __shared__ float sV[128 * 16];      // sV[kk*16 + r] = V-col (jp0+r) at k0+kk
    __shared__ float sb[128];

    for (int e = t; e < 128 * 16; e += 256) {
        const int kk = e >> 4, r = e & 15;
        const int k = k0 + kk;
        sV[e] = V[(k >> 3) * 2048 + (jp0 + r) * 8 + (k & 7)];
    }
    if (t < 128) sb[t] = bV[k0 + t];
    __syncthreads();

    float acc[4][4];
#pragma unroll
    for (int r = 0; r < 4; ++r)
#pragma unroll
        for (int c = 0; c < 4; ++c) acc[r][c] = 0.f;

    const float* Lbase = L + k0 * 256 + 4 * jq;  // coalesced b128 across wave
#pragma unroll 4
    for (int kk = 0; kk < 128; ++kk) {
        const float4 lq = *reinterpret_cast<const float4*>(Lbase + kk * 256);
        const float4 vf = *reinterpret_cast<const float4*>(&sV[kk * 16 + 4 * w]); // uniform b128 broadcast
        const float vr[4] = {vf.x, vf.y, vf.z, vf.w};
        const float lc[4] = {lq.x, lq.y, lq.z, lq.w};
#pragma unroll
        for (int r = 0; r < 4; ++r)
#pragma unroll
            for (int c = 0; c < 4; ++c) acc[r][c] += vr[r] * lc[c];
    }

#pragma unroll
    for (int r = 0; r < 4; ++r)
#pragma unroll
        for (int c = 0; c < 4; ++c)
            atomicAdd(&W2[(jp0 + 4 * w + r) * 256 + 4 * jq + c], acc[r][c]);

    // bias: wave 0 of the jp0==0 blocks re-walks its k-chunk (L is L2-warm).
    if (blockIdx.y == 0 && w == 0) {
        float ab[4] = {0.f, 0.f, 0.f, 0.f};
        for (int kk = 0; kk < 128; ++kk) {
            const float4 lq = *reinterpret_cast<const float4*>(Lbase + kk * 256);
            const float s = sb[kk];
            ab[0] += s * lq.x; ab[1] += s * lq.y;
            ab[2] += s * lq.z; ab[3] += s * lq.w;
        }
#pragma unroll
        for (int c = 0; c < 4; ++c) atomicAdd(&bvec[4 * jq + c], ab[c]);
    }
}

// Kernel 2: out[row][j] = bvec[j] + sum_j' v[row][j'] * W2[j'][j]
// grid = (4096/32 rows, 4 j-tiles of 64), block = 256 -> 512 blocks,
// ~2 blocks/CU, 8 waves/CU (2/SIMD). Thread: jq = t&15 -> j = j0+4*jq..+3;
// rg = t>>4 -> rows r0 = row0+2*rg, +1.
// v staged in LDS with row stride 260 (pad 4): within a wave the 4 rg
// groups read rows {2rg, 2rg+1}; (row*260+jp)%32 spreads them across
// distinct bank quads -> conflict-free ds_read_b128 broadcast.
// Per jp-quad: 2 LDS b128 + 4 lane-distinct W b128 (64-j slice, L2) ->
// 32 fmacs (16 MACs/LDS-inst).
#define SVLD 260   // padded row stride (floats); 260*4B = 16B-aligned
__global__ __launch_bounds__(256) void apply_w(
    const float* __restrict__ v,    // [4096, 256]
    const float* __restrict__ W2,   // [256, 256]
    const float* __restrict__ bvec, // [256]
    float* __restrict__ out)        // [4096, 256]
{
    const int t    = threadIdx.x;
    const int row0 = blockIdx.x * 32;
    const int j0   = blockIdx.y * 64;
    const int jq   = t & 15;                 // 0..15 -> j-quad in 64-j tile
    const int rg   = t >> 4;                 // 0..15 -> row pair
    const int jcol = j0 + 4 * jq;
    const int r0   = row0 + 2 * rg;

    __shared__ float sv[32 * SVLD];          // 32 rows, padded stride
    {
        // 32 rows x 64 float4 = 2048 float4, 8 per thread, coalesced loads.
        const float4* v4 = reinterpret_cast<const float4*>(v + row0 * 256);
#pragma unroll
        for (int e = t; e < 32 * 64; e += 256) {
            const int r = e >> 6, q = e & 63;
            *reinterpret_cast<float4*>(&sv[r * SVLD + 4 * q]) = v4[e];
        }
    }
    __syncthreads();

    const float4 bq = *reinterpret_cast<const float4*>(bvec + jcol);
    float4 acc0 = bq, acc1 = bq;

    const float* svr0 = sv + (2 * rg + 0) * SVLD;
    const float* svr1 = sv + (2 * rg + 1) * SVLD;
    const float* Wp   = W2 + jcol;

#pragma unroll 2
    for (int jp = 0; jp < 256; jp += 4) {
        const float4 w0 = *reinterpret_cast<const float4*>(Wp + (jp + 0) * 256);
        const float4 w1 = *reinterpret_cast<const float4*>(Wp + (jp + 1) * 256);
        const float4 w2 = *reinterpret_cast<const float4*>(Wp + (jp + 2) * 256);
        const float4 w3 = *reinterpret_cast<const float4*>(Wp + (jp + 3) * 256);
        const float4 a = *reinterpret_cast<const float4*>(svr0 + jp);
        const float4 b = *reinterpret_cast<const float4*>(svr1 + jp);

        acc0.x += a.x * w0.x + a.y * w1.x + a.z * w2.x + a.w * w3.x;
        acc0.y += a.x * w0.y + a.y * w1.y + a.z * w2.y + a.w * w3.y;
        acc0.z += a.x * w0.z + a.y * w1.z + a.z * w2.z + a.w * w3.z;
        acc0.w += a.x * w0.w + a.y * w1.w + a.z * w2.w + a.w * w3.w;

        acc1.x += b.x * w0.x + b.y * w1.x + b.z * w2.x + b.w * w3.x;
        acc1.y += b.x * w0.y + b.y * w1.y + b.z * w2.y + b.w * w3.y;
        acc1.z += b.x * w0.z + b.y * w1.z + b.z * w2.z + b.w * w3.z;
        acc1.w += b.x * w0.w + b.y * w1.w + b.z * w2.w + b.w * w3.w;
    }

    *reinterpret_cast<float4*>(out + (r0 + 0) * 256 + jcol) = acc0;
    *reinterpret_cast<float4*>(out + (r0 + 1) * 256 + jcol) = acc1;
}

extern "C" void kernel_launch(void* const* d_in, const int* in_sizes, int n_in,
                              void* d_out, int out_size, void* d_ws, size_t ws_size,
                              hipStream_t stream) {
    // setup_inputs order: q(0) k(1) v(2) bias(3) atten_mask(4) Q(5) K(6) V(7)
    //                     bias_Q(8) bias_K(9) bias_V(10) linear_output(11)
    const float* v_in = (const float*)d_in[2];
    const float* V_w  = (const float*)d_in[7];
    const float* bV   = (const float*)d_in[10];
    const float* L    = (const float*)d_in[11];

    float* W2   = (float*)d_ws;           // 256*256 floats
    float* bvec = W2 + 256 * 256;         // 256 floats

    hipMemsetAsync(d_ws, 0, (256 * 256 + 256) * sizeof(float), stream);
    compose_w<<<dim3(16, 16), 256, 0, stream>>>(V_w, bV, L, W2, bvec);
    apply_w<<<dim3(4096 / 32, 4), 256, 0, stream>>>(v_in, W2, bvec, (float*)d_out);
}

// Round 6
// 227.716 us; speedup vs baseline: 1.2366x; 1.0600x over previous
//
#include <hip/hip_runtime.h>

// B=4, N=1024, C=256, H=8.
// Reference math collapses: softmax over m sums to 1, and the final einsum
// 'bnmh,bnih->bnih' contracts only m of alpha -> out = vh elementwise.
// So: out[b,n,:] = linear_output^T @ flatten_ih(V-proj(v[b,n,:]) + bias_V)
// Precompose W[j'][j] = sum_{k=i*H+h} V[i,j',h] * L[k,j]  (256x256),
// bvec[j] = sum_k bias_V_flat[k] * L[k,j], then out = v @ W + bvec.
//
// R10 = CONTROL EXPERIMENT: byte-identical resubmission of the round-0
// kernel (measured 225.4 us). R6/R8/R9 (three different restructures with
// different pipe profiles) all landed 241-247 us, within 6 us of each
// other, while fills stayed 77-78 us every round. Either (1) all three
// restructures regressed ~equally (my pipe model is systematically wrong)
// or (2) dur_us drifts ~15 us round-to-round and we are at a harness
// floor. This A/B anchor distinguishes: ~225 -> (1), keep R0 structure
// and make single surgical changes; ~240 -> (2), declare roofline.

#define ROWS 8     // rows per block in apply kernel

// Kernel 1: split-K GEMM composing W and bvec into workspace (atomicAdd).
// grid = (16 k-chunks of 128, 16 j'-tiles of 16), block = 256 (j).
__global__ __launch_bounds__(256) void compose_w(
    const float* __restrict__ V,    // [C, C, H] : V[i*2048 + j'*8 + h]
    const float* __restrict__ bV,   // [C, H] flat = [2048]
    const float* __restrict__ L,    // [2048, 256]
    float* __restrict__ W2,         // [256*256] (zeroed)
    float* __restrict__ bvec)       // [256] (zeroed)
{
    const int j   = threadIdx.x;
    const int k0  = blockIdx.x * 128;
    const int jp0 = blockIdx.y * 16;

    __shared__ float sV[128 * 16];  // sV[kk][r] = Vr[k0+kk][jp0+r]
    __shared__ float sb[128];

    for (int e = threadIdx.x; e < 128 * 16; e += 256) {
        const int kk = e >> 4, r = e & 15;
        const int k = k0 + kk;
        sV[e] = V[(k >> 3) * 2048 + (jp0 + r) * 8 + (k & 7)];
    }
    if (threadIdx.x < 128) sb[threadIdx.x] = bV[k0 + threadIdx.x];
    __syncthreads();

    float acc[16];
#pragma unroll
    for (int r = 0; r < 16; ++r) acc[r] = 0.f;
    float accb = 0.f;

    const float* Lp = L + k0 * 256 + j;
    for (int kk = 0; kk < 128; ++kk) {
        const float lv = Lp[kk * 256];          // coalesced, L2-resident
        accb += sb[kk] * lv;
#pragma unroll
        for (int r = 0; r < 16; ++r) acc[r] += sV[kk * 16 + r] * lv;  // LDS broadcast
    }
#pragma unroll
    for (int r = 0; r < 16; ++r)
        atomicAdd(&W2[(jp0 + r) * 256 + j], acc[r]);
    if (blockIdx.y == 0) atomicAdd(&bvec[j], accb);
}

// Kernel 2: out[row][j] = bvec[j] + sum_j' v[row][j'] * W2[j'][j]
// grid = 4096/ROWS blocks, block = 256 (j).
__global__ __launch_bounds__(256) void apply_w(
    const float* __restrict__ v,    // [4096, 256]
    const float* __restrict__ W2,   // [256, 256]
    const float* __restrict__ bvec, // [256]
    float* __restrict__ out)        // [4096, 256]
{
    const int j = threadIdx.x;
    const int row0 = blockIdx.x * ROWS;

    __shared__ float sv[ROWS * 256];
    // float4 staging: ROWS*256 floats = ROWS*64 float4s, coalesced dwordx4
    {
        const float4* v4 = reinterpret_cast<const float4*>(v + row0 * 256);
        float4* sv4 = reinterpret_cast<float4*>(sv);
#pragma unroll
        for (int e = threadIdx.x; e < ROWS * 64; e += 256)
            sv4[e] = v4[e];
    }
    __syncthreads();

    const float b = bvec[j];
    float acc[ROWS];
#pragma unroll
    for (int r = 0; r < ROWS; ++r) acc[r] = b;

    const float* Wp = W2 + j;
    for (int jp = 0; jp < 256; jp += 4) {
        // 4 coalesced, L2-resident W reads (independent -> overlapped)
        const float w0 = Wp[(jp + 0) * 256];
        const float w1 = Wp[(jp + 1) * 256];
        const float w2 = Wp[(jp + 2) * 256];
        const float w3 = Wp[(jp + 3) * 256];
#pragma unroll
        for (int r = 0; r < ROWS; ++r) {
            const float4 s = *reinterpret_cast<const float4*>(&sv[r * 256 + jp]);  // ds_read_b128 broadcast
            acc[r] += s.x * w0 + s.y * w1 + s.z * w2 + s.w * w3;
        }
    }
#pragma unroll
    for (int r = 0; r < ROWS; ++r)
        out[(row0 + r) * 256 + j] = acc[r];
}

extern "C" void kernel_launch(void* const* d_in, const int* in_sizes, int n_in,
                              void* d_out, int out_size, void* d_ws, size_t ws_size,
                              hipStream_t stream) {
    // setup_inputs order: q(0) k(1) v(2) bias(3) atten_mask(4) Q(5) K(6) V(7)
    //                     bias_Q(8) bias_K(9) bias_V(10) linear_output(11)
    const float* v_in = (const float*)d_in[2];
    const float* V_w  = (const float*)d_in[7];
    const float* bV   = (const float*)d_in[10];
    const float* L    = (const float*)d_in[11];

    float* W2   = (float*)d_ws;           // 256*256 floats
    float* bvec = W2 + 256 * 256;         // 256 floats

    hipMemsetAsync(d_ws, 0, (256 * 256 + 256) * sizeof(float), stream);
    compose_w<<<dim3(16, 16), 256, 0, stream>>>(V_w, bV, L, W2, bvec);
    apply_w<<<4096 / ROWS, 256, 0, stream>>>(v_in, W2, bvec, (float*)d_out);
}